// Round 10
// baseline (484.133 us; speedup 1.0000x reference)
//
#include <hip/hip_runtime.h>
#include <hip/hip_cooperative_groups.h>
#include <math.h>

namespace cg = cooperative_groups;

#define LR 0.001f

// Sizes
#define B   64
#define IN  2048
#define HID 512
#define OUT 128
#define GB  16
#define NG  (B/GB)
#define NBLK 256
#define NTHR 512

typedef float vf2 __attribute__((ext_vector_type(2)));
typedef float vf4 __attribute__((ext_vector_type(4)));

// coop ws layout (floats)
#define WS_ZP   0                          // [2][GB][32][HID] = 524288 (dbuf)
#define WS_ZOP  (WS_ZP + 2*GB*32*HID)      // [GB][4][OUT] = 8192
#define WS_TH   (WS_ZOP + GB*4*OUT)        // [GB][HID]    = 8192
#define WS_GBW  (WS_TH + GB*HID)           // [B][HID]     = 32768

// fallback ws layout (mutually exclusive with coop)
#define FQC    16
#define FWS_ZP    0
#define FWS_TANH  (FWS_ZP + B*FQC*HID)
#define FWS_ZOP   (FWS_TANH + B*HID)
#define FWS_GB    (FWS_ZOP + B*8*OUT)

// out layout (floats)
#define O_L2N   0
#define O_DW0   (B*OUT)
#define O_DB0   (O_DW0 + B*IN*HID)
#define O_DW1   (O_DB0 + B*HID)
#define O_DB1   (O_DW1 + B*HID*OUT)

// ===================== cooperative mega-kernel =====================

// fwd1: units u in [ustart,ustart+ucount); unit = (bl = u>>5, qc = u&31) = 64 q rows.
// 512 thr: sub=tid>>7 owns 16 q; thread float4 at h=(tid&127)*4; LDS-reduce subs.
__device__ __forceinline__ void fwd1_units(const float* __restrict__ x,
                                           const float* __restrict__ W0,
                                           const float* __restrict__ dW0,
                                           float* __restrict__ zp, float* lds,
                                           int bb, int par, int ustart, int ucount,
                                           int wrank, int wcount, int tid) {
    const int sub = tid >> 7;
    const int hq = tid & 127;
    const int h = hq << 2;
    for (int u = ustart + wrank; u < ustart + ucount; u += wcount) {
        const int bl = u >> 5;
        const int b = bb + bl;
        const int q0 = (u & 31) * 64 + sub * 16;
        const float* xr = x + b * IN;
        float4 acc = make_float4(0.f, 0.f, 0.f, 0.f);
        #pragma unroll 4
        for (int qi = 0; qi < 16; ++qi) {
            const int q = q0 + qi;
            const float xv = xr[q];
            const float4 w0 = *(const float4*)(W0 + q * HID + h);
            const float4 dw = *(const float4*)(dW0 + ((size_t)(b * IN + q)) * HID + h);
            acc.x += xv * (w0.x + dw.x);
            acc.y += xv * (w0.y + dw.y);
            acc.z += xv * (w0.z + dw.z);
            acc.w += xv * (w0.w + dw.w);
        }
        *(float4*)(lds + sub * HID + h) = acc;
        __syncthreads();
        if (sub == 0) {
            const float4 a1 = *(float4*)(lds + 1 * HID + h);
            const float4 a2 = *(float4*)(lds + 2 * HID + h);
            const float4 a3 = *(float4*)(lds + 3 * HID + h);
            acc.x += a1.x + a2.x + a3.x;
            acc.y += a1.y + a2.y + a3.y;
            acc.z += a1.z + a2.z + a3.z;
            acc.w += a1.w + a2.w + a3.w;
            *(float4*)(zp + (((size_t)par * GB + bl) * 32 + (u & 31)) * HID + h) = acc;
        }
        __syncthreads();
    }
}

// upd0 over b range [b0_, b0_+nb): new_dW0 = dW0 - LR*x*gb. Reads L3-hot, NT stores.
__device__ __forceinline__ void upd0_range(const float* __restrict__ dW0,
                                           const float* __restrict__ x,
                                           const float* __restrict__ gbw,
                                           float* __restrict__ out_dW0,
                                           int b0_, int nb, int rank, int cnt, int tid) {
    const int n4 = nb * IN * (HID / 4);
    const size_t base4 = (size_t)b0_ * IN * (HID / 4);
    for (int i = rank * NTHR + tid; i < n4; i += cnt * NTHR) {
        const int h4 = i & (HID / 4 - 1);
        const int rest = i >> 7;
        const int q = rest & (IN - 1);
        const int b = b0_ + (rest >> 11);
        const size_t j = base4 + i;
        const float4 dw = ((const float4*)dW0)[j];
        const float xv = x[b * IN + q];
        const float4 g = *(const float4*)(gbw + b * HID + h4 * 4);
        vf4 o;
        o.x = dw.x - LR * xv * g.x;
        o.y = dw.y - LR * xv * g.y;
        o.z = dw.z - LR * xv * g.z;
        o.w = dw.w - LR * xv * g.w;
        __builtin_nontemporal_store(o, (vf4*)out_dW0 + j);
    }
}

// P1: block pbl = (bl = pbl>>2, slice sl = pbl&3, 128 h each): tanh + zo-partials.
__device__ __forceinline__ void p1_work(const float* __restrict__ W1,
                                        const float* __restrict__ dW1,
                                        const float* __restrict__ bias0,
                                        const float* __restrict__ db0,
                                        const float* __restrict__ zp,
                                        float* __restrict__ zop,
                                        float* __restrict__ tanhw, float* lds,
                                        int bb, int par, int pbl, int tid) {
    const int bl = pbl >> 2, sl = pbl & 3;
    const int b = bb + bl;
    const int hs = sl * 128;
    const int sub = tid >> 7, hq = tid & 127;
    // A: z-sum over 32 chunks + bias + tanh
    {
        float zs = 0.f;
        const float* p = zp + (((size_t)par * GB + bl) * 32) * HID + hs + hq;
        #pragma unroll
        for (int k = 0; k < 8; ++k) zs += p[(size_t)(sub * 8 + k) * HID];
        lds[sub * 128 + hq] = zs;
    }
    __syncthreads();
    if (tid < 128) {
        const int h = hs + tid;
        const float z = lds[tid] + lds[128 + tid] + lds[256 + tid] + lds[384 + tid]
                      + bias0[h] + db0[b * HID + h];
        const float th = tanhf(z);
        tanhw[bl * HID + h] = th;
        lds[tid] = th;                 // each thread only rewrites its own slot
    }
    __syncthreads();
    // B: zo partials: sub owns 32 h of the slice, o = tid&127
    {
        const int o = tid & 127;
        float acc = 0.f;
        #pragma unroll 4
        for (int k = 0; k < 32; ++k) {
            const int hl = sub * 32 + k;
            const float th = lds[hl];
            const int h = hs + hl;
            acc += th * (W1[h * OUT + o] + dW1[((size_t)b * HID + h) * OUT + o]);
        }
        __syncthreads();
        lds[sub * 128 + o] = acc;
        __syncthreads();
        if (tid < 128)
            zop[(bl * 4 + sl) * OUT + tid] =
                lds[tid] + lds[128 + tid] + lds[256 + tid] + lds[384 + tid];
    }
}

// P2: stats + g2 (redundant per slice-block) + bwd over 128 h rows.
__device__ __forceinline__ void p2_work(const float* __restrict__ W1,
                                        const float* __restrict__ dW1,
                                        const float* __restrict__ bias1,
                                        const float* __restrict__ db1,
                                        const float* __restrict__ ut,
                                        const float* __restrict__ db0,
                                        const float* __restrict__ zop,
                                        const float* __restrict__ tanhw,
                                        float* __restrict__ gbw,
                                        float* __restrict__ out, float* lds,
                                        int bb, int pbl, int tid) {
    const int bl = pbl >> 2, sl = pbl & 3;
    const int b = bb + bl;
    float* SG2 = lds + 2048;
    float* SRED = lds + 2176;
    if (tid < 128) {
        const int o = tid;
        const float zo = zop[(bl * 4 + 0) * OUT + o] + zop[(bl * 4 + 1) * OUT + o]
                       + zop[(bl * 4 + 2) * OUT + o] + zop[(bl * 4 + 3) * OUT + o]
                       + bias1[o] + db1[b * OUT + o];
        const float tr = ut[b * OUT + o];
        float a = zo * zo, c2 = tr * tr, d = tr * zo;
        for (int off = 32; off; off >>= 1) {
            a  += __shfl_xor(a,  off, 64);
            c2 += __shfl_xor(c2, off, 64);
            d  += __shfl_xor(d,  off, 64);
        }
        const int wv = tid >> 6;
        if ((tid & 63) == 0) { SRED[wv * 3] = a; SRED[wv * 3 + 1] = c2; SRED[wv * 3 + 2] = d; }
        lds[o] = zo;
    }
    __syncthreads();
    const float l2 = SRED[0] + SRED[3];
    const float ntv = fmaxf(sqrtf(SRED[1] + SRED[4]), 1e-12f);
    const float tdot = (SRED[2] + SRED[5]) / ntv;
    const float s = 2.0f * tdot / (l2 * l2);
    if (tid < 128) {
        const int o = tid;
        const float zo = lds[o];
        const float tr = ut[b * OUT + o];
        const float g2 = -(tr / ntv) / l2 + s * zo;
        SG2[o] = g2;
        if (sl == 0) {
            out[O_L2N + b * OUT + o] = zo / l2;
            out[O_DB1 + b * OUT + o] = db1[b * OUT + o] - LR * g2;
        }
    }
    __syncthreads();
    const int wv = tid >> 6, lane = tid & 63, o2 = lane * 2;
    const float g2x = SG2[o2], g2y = SG2[o2 + 1];
    for (int i = 0; i < 16; ++i) {
        const int h = sl * 128 + wv * 16 + i;
        const size_t idx = ((size_t)b * HID + h) * OUT + o2;
        const float2 dw = *(const float2*)(dW1 + idx);
        const float2 w1 = *(const float2*)(W1 + h * OUT + o2);
        float part = g2x * (w1.x + dw.x) + g2y * (w1.y + dw.y);
        for (int off = 32; off; off >>= 1) part += __shfl_xor(part, off, 64);
        const float th = tanhw[bl * HID + h];
        vf2 nd;
        nd.x = dw.x - LR * th * g2x;
        nd.y = dw.y - LR * th * g2y;
        __builtin_nontemporal_store(nd, (vf2*)(out + O_DW1 + idx));
        if (lane == 0) {
            const float gbv = (1.f - th * th) * part;
            gbw[b * HID + h] = gbv;
            out[O_DB0 + b * HID + h] = db0[b * HID + h] - LR * gbv;
        }
    }
}

__global__ __launch_bounds__(NTHR, 2)
void k_mega(const float* x, const float* ut, const float* W0, const float* bias0,
            const float* W1, const float* bias1, const float* dW0, const float* db0,
            const float* dW1, const float* db1, float* out,
            float* zp, float* zop, float* tanhw, float* gbw) {
    cg::grid_group grid = cg::this_grid();
    __shared__ float lds[2192];
    const int bid = blockIdx.x, tid = threadIdx.x;

    // A0: fwd1(group 0), all 256 blocks, 512 units, parity 0
    fwd1_units(x, W0, dW0, zp, lds, 0, 0, 0, 512, bid, NBLK, tid);

    for (int g = 0; g < NG; ++g) {
        const int bb = g * GB;
        const int parN = (g + 1) & 1;
        grid.sync();
        // X: P1_g || fwd1(g+1) half-A || upd0(g-1) half-A
        if (bid < 64) {
            p1_work(W1, dW1, bias0, db0, zp, zop, tanhw, lds, bb, g & 1, bid, tid);
        } else if (g == 0) {
            fwd1_units(x, W0, dW0, zp, lds, bb + GB, parN, 0, 256, bid - 64, 192, tid);
        } else if (g < NG - 1) {
            if (bid < 160)
                fwd1_units(x, W0, dW0, zp, lds, bb + GB, parN, 0, 256, bid - 64, 96, tid);
            else
                upd0_range(dW0, x, gbw, out + O_DW0, bb - GB, 8, bid - 160, 96, tid);
        } else {
            upd0_range(dW0, x, gbw, out + O_DW0, bb - GB, 8, bid - 64, 192, tid);
        }
        grid.sync();
        // Y: P2_g || fwd1(g+1) half-B || upd0(g-1) half-B
        if (bid < 64) {
            p2_work(W1, dW1, bias1, db1, ut, db0, zop, tanhw, gbw, out, lds, bb, bid, tid);
        } else if (g == 0) {
            fwd1_units(x, W0, dW0, zp, lds, bb + GB, parN, 256, 256, bid - 64, 192, tid);
        } else if (g < NG - 1) {
            if (bid < 160)
                fwd1_units(x, W0, dW0, zp, lds, bb + GB, parN, 256, 256, bid - 64, 96, tid);
            else
                upd0_range(dW0, x, gbw, out + O_DW0, bb - GB + 8, 8, bid - 160, 96, tid);
        } else {
            upd0_range(dW0, x, gbw, out + O_DW0, bb - GB + 8, 8, bid - 64, 192, tid);
        }
    }
    grid.sync();
    // Z: upd0(group 3), all blocks
    upd0_range(dW0, x, gbw, out + O_DW0, 3 * GB, GB, bid, NBLK, tid);
}

// ===================== fallback (proven ~162-164 us) =====================

__global__ void k_fwd1f(const float* __restrict__ x, const float* __restrict__ W0,
                        const float* __restrict__ dW0, float* __restrict__ zp) {
    const int b = blockIdx.x;
    const int q0 = blockIdx.y * (IN / FQC);
    const int h = threadIdx.x * 4;
    const float* xr = x + b * IN;
    float4 acc = make_float4(0.f, 0.f, 0.f, 0.f);
    for (int qi = 0; qi < IN / FQC; ++qi) {
        const int q = q0 + qi;
        const float xv = xr[q];
        const float4 w0 = *(const float4*)(W0 + q * HID + h);
        const float4 dw = *(const float4*)(dW0 + ((size_t)(b * IN + q)) * HID + h);
        acc.x += xv * (w0.x + dw.x);
        acc.y += xv * (w0.y + dw.y);
        acc.z += xv * (w0.z + dw.z);
        acc.w += xv * (w0.w + dw.w);
    }
    *(float4*)(zp + (b * FQC + blockIdx.y) * HID + h) = acc;
}

__global__ void k_fwd2f(const float* __restrict__ zp, const float* __restrict__ b0,
                        const float* __restrict__ db0, const float* __restrict__ W1,
                        const float* __restrict__ dW1, float* __restrict__ tanhv,
                        float* __restrict__ zop) {
    const int b = blockIdx.x;
    const int h0 = blockIdx.y * 64;
    const int tid = threadIdx.x;
    __shared__ float sth[64];
    if (tid < 64) {
        const int h = h0 + tid;
        float zsum = 0.f;
        const float* p = zp + (b * FQC) * HID + h;
        #pragma unroll
        for (int qc = 0; qc < FQC; ++qc) zsum += p[qc * HID];
        const float th = tanhf(zsum + b0[h] + db0[b * HID + h]);
        tanhv[b * HID + h] = th;
        sth[tid] = th;
    }
    __syncthreads();
    const int o = tid;
    float acc = 0.f;
    #pragma unroll 8
    for (int hi = 0; hi < 64; ++hi) {
        const int h = h0 + hi;
        acc += sth[hi] * (W1[h * OUT + o] + dW1[(b * HID + h) * OUT + o]);
    }
    zop[(b * 8 + blockIdx.y) * OUT + o] = acc;
}

__global__ void k_bwd1f(const float* __restrict__ zop, const float* __restrict__ b1,
                        const float* __restrict__ db1, const float* __restrict__ ut,
                        const float* __restrict__ W1, const float* __restrict__ dW1,
                        const float* __restrict__ tanhv, const float* __restrict__ db0,
                        float* __restrict__ out_l2n, float* __restrict__ out_db1,
                        float* __restrict__ out_dW1, float* __restrict__ out_db0,
                        float* __restrict__ gb) {
    const int b = blockIdx.x;
    const int w = threadIdx.x >> 6;
    const int lane = threadIdx.x & 63;
    const int o2 = lane * 2;
    float2 zo;
    zo.x = b1[o2]     + db1[b * OUT + o2];
    zo.y = b1[o2 + 1] + db1[b * OUT + o2 + 1];
    #pragma unroll
    for (int c = 0; c < 8; ++c) {
        const float2 zp2 = *(const float2*)(zop + (b * 8 + c) * OUT + o2);
        zo.x += zp2.x; zo.y += zp2.y;
    }
    const float2 tr = *(const float2*)(ut + b * OUT + o2);
    float a = zo.x * zo.x + zo.y * zo.y;
    float c2 = tr.x * tr.x + tr.y * tr.y;
    float d  = tr.x * zo.x + tr.y * zo.y;
    for (int off = 32; off; off >>= 1) {
        a  += __shfl_xor(a,  off, 64);
        c2 += __shfl_xor(c2, off, 64);
        d  += __shfl_xor(d,  off, 64);
    }
    const float l2 = a;
    const float nt = fmaxf(sqrtf(c2), 1e-12f);
    const float tdot = d / nt;
    const float s = 2.0f * tdot / (l2 * l2);
    float2 g2;
    g2.x = -(tr.x / nt) / l2 + s * zo.x;
    g2.y = -(tr.y / nt) / l2 + s * zo.y;
    if (blockIdx.y == 0 && w == 0) {
        *(float2*)(out_l2n + b * OUT + o2) = make_float2(zo.x / l2, zo.y / l2);
        *(float2*)(out_db1 + b * OUT + o2) =
            make_float2(db1[b * OUT + o2] - LR * g2.x, db1[b * OUT + o2 + 1] - LR * g2.y);
    }
    for (int i = 0; i < 16; ++i) {
        const int h = blockIdx.y * 64 + w * 16 + i;
        const int idx = (b * HID + h) * OUT + o2;
        const float2 dw = *(const float2*)(dW1 + idx);
        const float2 w1 = *(const float2*)(W1 + h * OUT + o2);
        float part = g2.x * (w1.x + dw.x) + g2.y * (w1.y + dw.y);
        for (int off = 32; off; off >>= 1) part += __shfl_xor(part, off, 64);
        const float th = tanhv[b * HID + h];
        vf2 nd;
        nd.x = dw.x - LR * th * g2.x;
        nd.y = dw.y - LR * th * g2.y;
        __builtin_nontemporal_store(nd, (vf2*)(out_dW1 + idx));
        if (lane == 0) {
            const float gbv = (1.f - th * th) * part;
            gb[b * HID + h] = gbv;
            out_db0[b * HID + h] = db0[b * HID + h] - LR * gbv;
        }
    }
}

__global__ void k_upd0f(const float* __restrict__ dW0, const float* __restrict__ x,
                        const float* __restrict__ gb, float* __restrict__ out_dW0) {
    const int n4 = B * IN * HID / 4;
    const int stride = gridDim.x * blockDim.x;
    for (int i = blockIdx.x * blockDim.x + threadIdx.x; i < n4; i += stride) {
        const int j = n4 - 1 - i;
        const int h4 = j & (HID / 4 - 1);
        const int rest = j >> 7;
        const int q = rest & (IN - 1);
        const int b = rest >> 11;
        const float4 dw = ((const float4*)dW0)[j];
        const float xv = x[b * IN + q];
        const float4 g = *(const float4*)(gb + b * HID + h4 * 4);
        vf4 o;
        o.x = dw.x - LR * xv * g.x;
        o.y = dw.y - LR * xv * g.y;
        o.z = dw.z - LR * xv * g.z;
        o.w = dw.w - LR * xv * g.w;
        __builtin_nontemporal_store(o, (vf4*)out_dW0 + j);
    }
}

extern "C" void kernel_launch(void* const* d_in, const int* in_sizes, int n_in,
                              void* d_out, int out_size, void* d_ws, size_t ws_size,
                              hipStream_t stream) {
    (void)in_sizes; (void)n_in; (void)out_size; (void)ws_size;
    const float* x   = (const float*)d_in[0];
    const float* ut  = (const float*)d_in[1];
    const float* W0  = (const float*)d_in[2];
    const float* b0  = (const float*)d_in[3];
    const float* W1  = (const float*)d_in[4];
    const float* b1  = (const float*)d_in[5];
    const float* dW0 = (const float*)d_in[6];
    const float* db0 = (const float*)d_in[7];
    const float* dW1 = (const float*)d_in[8];
    const float* db1 = (const float*)d_in[9];

    float* ws  = (float*)d_ws;
    float* out = (float*)d_out;
    float* zp  = ws + WS_ZP;
    float* zop = ws + WS_ZOP;
    float* th  = ws + WS_TH;
    float* gbw = ws + WS_GBW;

    void* args[] = {(void*)&x, (void*)&ut, (void*)&W0, (void*)&b0, (void*)&W1,
                    (void*)&b1, (void*)&dW0, (void*)&db0, (void*)&dW1, (void*)&db1,
                    (void*)&out, (void*)&zp, (void*)&zop, (void*)&th, (void*)&gbw};
    hipError_t err = hipLaunchCooperativeKernel((void*)k_mega, dim3(NBLK), dim3(NTHR),
                                                args, 0, stream);
    if (err != hipSuccess) {
        (void)hipGetLastError();
        k_fwd1f<<<dim3(B, FQC), 128, 0, stream>>>(x, W0, dW0, ws + FWS_ZP);
        k_fwd2f<<<dim3(B, 8), 128, 0, stream>>>(ws + FWS_ZP, b0, db0, W1, dW1,
                                                ws + FWS_TANH, ws + FWS_ZOP);
        k_bwd1f<<<dim3(B, 8), 256, 0, stream>>>(ws + FWS_ZOP, b1, db1, ut, W1, dW1,
                                                ws + FWS_TANH, db0,
                                                out + O_L2N, out + O_DB1,
                                                out + O_DW1, out + O_DB0, ws + FWS_GB);
        k_upd0f<<<dim3(4096), 256, 0, stream>>>(dW0, x, ws + FWS_GB, out + O_DW0);
    }
}

// Round 11
// 297.065 us; speedup vs baseline: 1.6297x; 1.6297x over previous
//
#include <hip/hip_runtime.h>
#include <math.h>

#define LR 0.001f

// Sizes
#define B   64
#define IN  2048
#define HID 512
#define OUT 128
#define NC  32          // clusters
#define CB  8           // blocks per cluster
#define NBLK 256
#define NTHR 512

typedef float vf2 __attribute__((ext_vector_type(2)));
typedef float vf4 __attribute__((ext_vector_type(4)));

// coop ws layout (floats)
#define WS_ZPART  0                         // [64][8][512] = 262144
#define WS_ZOPART (WS_ZPART + B*CB*HID)     // [64][8][128] = 65536
#define WS_GBW    (WS_ZOPART + B*CB*OUT)    // [64][512]    = 32768
#define WS_CTR    (WS_GBW + B*HID)          // 32*8 ints
// fallback layout (mutually exclusive per replay; fully rewritten before read)
#define FQC    16
#define FWS_ZP    0
#define FWS_TANH  (FWS_ZP + B*FQC*HID)
#define FWS_ZOP   (FWS_TANH + B*HID)
#define FWS_GB    (FWS_ZOP + B*8*OUT)

// out layout (floats)
#define O_L2N   0
#define O_DW0   (B*OUT)
#define O_DB0   (O_DW0 + B*IN*HID)
#define O_DW1   (O_DB0 + B*HID)
#define O_DB1   (O_DW1 + B*HID*OUT)

// ---- 8-block cluster barrier: AGENT-scope release/acquire, thread0 spins.
__device__ __forceinline__ void cbar(int* c, int tid) {
    __syncthreads();
    if (tid == 0) {
        __hip_atomic_fetch_add(c, 1, __ATOMIC_RELEASE, __HIP_MEMORY_SCOPE_AGENT);
        while (__hip_atomic_load(c, __ATOMIC_ACQUIRE, __HIP_MEMORY_SCOPE_AGENT) < CB) {
            __builtin_amdgcn_s_sleep(1);
        }
    }
    __syncthreads();
}

// ===================== cluster mega-kernel =====================
// 32 clusters x 8 blocks; cluster cid handles b = cid, then b = cid+32.
// Cluster blocks share one XCD (bid&7 swizzle) -> barrier + slab reuse in L2.
__global__ __launch_bounds__(NTHR, 2)
void k_mega(const float* __restrict__ x, const float* __restrict__ ut,
            const float* __restrict__ W0, const float* __restrict__ bias0,
            const float* __restrict__ W1, const float* __restrict__ bias1,
            const float* __restrict__ dW0, const float* __restrict__ db0,
            const float* __restrict__ dW1, const float* __restrict__ db1,
            float* __restrict__ out, float* __restrict__ zpart,
            float* __restrict__ zopart, float* __restrict__ gbw,
            int* __restrict__ ctrs) {
    const int bid = blockIdx.x, tid = threadIdx.x;
    const int xcd = bid & 7;
    const int slot = bid >> 3;                 // 0..31
    const int cid = xcd * 4 + (slot >> 3);     // 0..31
    const int cj  = slot & 7;                  // 0..7 block-in-cluster
    int* ctr = ctrs + cid * 8;

    __shared__ float sth[64];
    __shared__ float buf[2048];
    __shared__ float sg2[128];
    __shared__ float sredl[8];

    for (int pass = 0; pass < 2; ++pass) {
        const int b = cid + pass * NC;
        const int hs = cj * 64;                // h-slab for P23/P45

        // ---- P1: z partials for q-slab [cj*256, cj*256+256) ----
        __syncthreads();                       // protect buf reuse across passes
        {
            const int sub = tid >> 7;          // 0..3 (64 q each)
            const int h = (tid & 127) << 2;
            const int q0 = cj * 256 + sub * 64;
            const float* xr = x + b * IN;
            float4 acc = make_float4(0.f, 0.f, 0.f, 0.f);
            #pragma unroll 4
            for (int qi = 0; qi < 64; ++qi) {
                const int q = q0 + qi;
                const float xv = xr[q];
                const float4 w0 = *(const float4*)(W0 + q * HID + h);
                const float4 dw = *(const float4*)(dW0 + ((size_t)(b * IN + q)) * HID + h);
                acc.x += xv * (w0.x + dw.x);
                acc.y += xv * (w0.y + dw.y);
                acc.z += xv * (w0.z + dw.z);
                acc.w += xv * (w0.w + dw.w);
            }
            *(float4*)(buf + sub * HID + h) = acc;
            __syncthreads();
            if (sub == 0) {
                const float4 a1 = *(float4*)(buf + 1 * HID + h);
                const float4 a2 = *(float4*)(buf + 2 * HID + h);
                const float4 a3 = *(float4*)(buf + 3 * HID + h);
                acc.x += a1.x + a2.x + a3.x;
                acc.y += a1.y + a2.y + a3.y;
                acc.z += a1.z + a2.z + a3.z;
                acc.w += a1.w + a2.w + a3.w;
                *(float4*)(zpart + (size_t)(b * CB + cj) * HID + h) = acc;
            }
        }
        cbar(ctr + pass * 3 + 0, tid);

        // ---- P23: tanh for h-slab + zo partials over h-slab ----
        if (tid < 64) {
            const int h = hs + tid;
            float zs = 0.f;
            #pragma unroll
            for (int k = 0; k < CB; ++k) zs += zpart[(size_t)(b * CB + k) * HID + h];
            sth[tid] = tanhf(zs + bias0[h] + db0[b * HID + h]);
        }
        __syncthreads();
        {
            const int sub = tid >> 7;          // 0..3 (16 h each)
            const int o = tid & 127;
            float acc = 0.f;
            #pragma unroll 4
            for (int k = 0; k < 16; ++k) {
                const int hl = sub * 16 + k;
                const int h = hs + hl;
                acc += sth[hl] * (W1[h * OUT + o] + dW1[((size_t)b * HID + h) * OUT + o]);
            }
            buf[sub * 128 + o] = acc;
            __syncthreads();
            if (tid < 128)
                zopart[(b * CB + cj) * OUT + tid] =
                    buf[tid] + buf[128 + tid] + buf[256 + tid] + buf[384 + tid];
        }
        cbar(ctr + pass * 3 + 1, tid);

        // ---- P45: redundant stats/g2 + bwd over h-slab ----
        if (tid < 128) {
            const int o = tid;
            float zo = bias1[o] + db1[b * OUT + o];
            #pragma unroll
            for (int k = 0; k < CB; ++k) zo += zopart[(b * CB + k) * OUT + o];
            const float tr = ut[b * OUT + o];
            float a = zo * zo, c2 = tr * tr, d = tr * zo;
            for (int off = 32; off; off >>= 1) {
                a  += __shfl_xor(a,  off, 64);
                c2 += __shfl_xor(c2, off, 64);
                d  += __shfl_xor(d,  off, 64);
            }
            const int wv = tid >> 6;
            if ((tid & 63) == 0) { sredl[wv * 3] = a; sredl[wv * 3 + 1] = c2; sredl[wv * 3 + 2] = d; }
            buf[o] = zo;
        }
        __syncthreads();
        const float l2  = sredl[0] + sredl[3];              // squared norm (as in source)
        const float ntv = fmaxf(sqrtf(sredl[1] + sredl[4]), 1e-12f);
        const float tdot = (sredl[2] + sredl[5]) / ntv;
        const float sc = 2.0f * tdot / (l2 * l2);
        if (tid < 128) {
            const int o = tid;
            const float zo = buf[o];
            const float tr = ut[b * OUT + o];
            const float g2 = -(tr / ntv) / l2 + sc * zo;
            sg2[o] = g2;
            if (cj == 0) {
                out[O_L2N + b * OUT + o] = zo / l2;
                out[O_DB1 + b * OUT + o] = db1[b * OUT + o] - LR * g2;
            }
        }
        __syncthreads();
        {
            const int wv = tid >> 6, lane = tid & 63, o2 = lane * 2;
            const float g2x = sg2[o2], g2y = sg2[o2 + 1];
            for (int i = 0; i < 8; ++i) {
                const int hl = wv * 8 + i;
                const int h = hs + hl;
                const size_t idx = ((size_t)b * HID + h) * OUT + o2;
                const float2 dw = *(const float2*)(dW1 + idx);
                const float2 w1 = *(const float2*)(W1 + h * OUT + o2);
                float part = g2x * (w1.x + dw.x) + g2y * (w1.y + dw.y);
                for (int off = 32; off; off >>= 1) part += __shfl_xor(part, off, 64);
                const float th = sth[hl];
                vf2 nd;
                nd.x = dw.x - LR * th * g2x;
                nd.y = dw.y - LR * th * g2y;
                __builtin_nontemporal_store(nd, (vf2*)(out + O_DW1 + idx));
                if (lane == 0) {
                    const float gbv = (1.f - th * th) * part;
                    gbw[b * HID + h] = gbv;
                    out[O_DB0 + b * HID + h] = db0[b * HID + h] - LR * gbv;
                }
            }
        }
        cbar(ctr + pass * 3 + 2, tid);

        // ---- P6: upd0 for q-slab (dW0 slab L2/L3-hot from P1) ----
        buf[tid] = gbw[b * HID + tid];          // gb[512]
        if (tid < 256) buf[512 + tid] = x[b * IN + cj * 256 + tid];
        __syncthreads();
        {
            const size_t base4 = ((size_t)b * IN + cj * 256) * (HID / 4);
            const vf4* dW0v = (const vf4*)dW0;
            vf4* outv = (vf4*)(out + O_DW0);
            for (int it = 0; it < 64; ++it) {
                const int i = it * NTHR + tid;
                const int ql = i >> 7;
                const int h4 = i & 127;
                const vf4 dw = dW0v[base4 + i];
                const float xv = buf[512 + ql];
                const float4 g = *(const float4*)&buf[h4 * 4];
                vf4 o4;
                o4.x = dw.x - LR * xv * g.x;
                o4.y = dw.y - LR * xv * g.y;
                o4.z = dw.z - LR * xv * g.z;
                o4.w = dw.w - LR * xv * g.w;
                __builtin_nontemporal_store(o4, outv + base4 + i);
            }
        }
        // no cluster barrier needed before next pass (disjoint b)
    }
}

// ===================== fallback (proven ~162 us) =====================

__global__ void k_fwd1f(const float* __restrict__ x, const float* __restrict__ W0,
                        const float* __restrict__ dW0, float* __restrict__ zp) {
    const int b = blockIdx.x;
    const int q0 = blockIdx.y * (IN / FQC);
    const int h = threadIdx.x * 4;
    const float* xr = x + b * IN;
    float4 acc = make_float4(0.f, 0.f, 0.f, 0.f);
    for (int qi = 0; qi < IN / FQC; ++qi) {
        const int q = q0 + qi;
        const float xv = xr[q];
        const float4 w0 = *(const float4*)(W0 + q * HID + h);
        const float4 dw = *(const float4*)(dW0 + ((size_t)(b * IN + q)) * HID + h);
        acc.x += xv * (w0.x + dw.x);
        acc.y += xv * (w0.y + dw.y);
        acc.z += xv * (w0.z + dw.z);
        acc.w += xv * (w0.w + dw.w);
    }
    *(float4*)(zp + (b * FQC + blockIdx.y) * HID + h) = acc;
}

__global__ void k_fwd2f(const float* __restrict__ zp, const float* __restrict__ b0,
                        const float* __restrict__ db0, const float* __restrict__ W1,
                        const float* __restrict__ dW1, float* __restrict__ tanhv,
                        float* __restrict__ zop) {
    const int b = blockIdx.x;
    const int h0 = blockIdx.y * 64;
    const int tid = threadIdx.x;
    __shared__ float sth[64];
    if (tid < 64) {
        const int h = h0 + tid;
        float zsum = 0.f;
        #pragma unroll
        for (int qc = 0; qc < FQC; ++qc) zsum += zp[(b * FQC + qc) * HID + h];
        const float th = tanhf(zsum + b0[h] + db0[b * HID + h]);
        tanhv[b * HID + h] = th;
        sth[tid] = th;
    }
    __syncthreads();
    const int o = tid;
    float acc = 0.f;
    #pragma unroll 8
    for (int hi = 0; hi < 64; ++hi) {
        const int h = h0 + hi;
        acc += sth[hi] * (W1[h * OUT + o] + dW1[(b * HID + h) * OUT + o]);
    }
    zop[(b * 8 + blockIdx.y) * OUT + o] = acc;
}

__global__ void k_bwd1f(const float* __restrict__ zop, const float* __restrict__ b1,
                        const float* __restrict__ db1, const float* __restrict__ ut,
                        const float* __restrict__ W1, const float* __restrict__ dW1,
                        const float* __restrict__ tanhv, const float* __restrict__ db0,
                        float* __restrict__ out_l2n, float* __restrict__ out_db1,
                        float* __restrict__ out_dW1, float* __restrict__ out_db0,
                        float* __restrict__ gb) {
    const int b = blockIdx.x;
    const int w = threadIdx.x >> 6;
    const int lane = threadIdx.x & 63;
    const int o2 = lane * 2;
    float2 zo;
    zo.x = b1[o2]     + db1[b * OUT + o2];
    zo.y = b1[o2 + 1] + db1[b * OUT + o2 + 1];
    #pragma unroll
    for (int c = 0; c < 8; ++c) {
        const float2 zp2 = *(const float2*)(zop + (b * 8 + c) * OUT + o2);
        zo.x += zp2.x; zo.y += zp2.y;
    }
    const float2 tr = *(const float2*)(ut + b * OUT + o2);
    float a = zo.x * zo.x + zo.y * zo.y;
    float c2 = tr.x * tr.x + tr.y * tr.y;
    float d  = tr.x * zo.x + tr.y * zo.y;
    for (int off = 32; off; off >>= 1) {
        a  += __shfl_xor(a,  off, 64);
        c2 += __shfl_xor(c2, off, 64);
        d  += __shfl_xor(d,  off, 64);
    }
    const float l2 = a;
    const float nt = fmaxf(sqrtf(c2), 1e-12f);
    const float tdot = d / nt;
    const float s = 2.0f * tdot / (l2 * l2);
    float2 g2;
    g2.x = -(tr.x / nt) / l2 + s * zo.x;
    g2.y = -(tr.y / nt) / l2 + s * zo.y;
    if (blockIdx.y == 0 && w == 0) {
        *(float2*)(out_l2n + b * OUT + o2) = make_float2(zo.x / l2, zo.y / l2);
        *(float2*)(out_db1 + b * OUT + o2) =
            make_float2(db1[b * OUT + o2] - LR * g2.x, db1[b * OUT + o2 + 1] - LR * g2.y);
    }
    for (int i = 0; i < 16; ++i) {
        const int h = blockIdx.y * 64 + w * 16 + i;
        const int idx = (b * HID + h) * OUT + o2;
        const float2 dw = *(const float2*)(dW1 + idx);
        const float2 w1 = *(const float2*)(W1 + h * OUT + o2);
        float part = g2.x * (w1.x + dw.x) + g2.y * (w1.y + dw.y);
        for (int off = 32; off; off >>= 1) part += __shfl_xor(part, off, 64);
        const float th = tanhv[b * HID + h];
        vf2 nd;
        nd.x = dw.x - LR * th * g2.x;
        nd.y = dw.y - LR * th * g2.y;
        __builtin_nontemporal_store(nd, (vf2*)(out_dW1 + idx));
        if (lane == 0) {
            const float gbv = (1.f - th * th) * part;
            gb[b * HID + h] = gbv;
            out_db0[b * HID + h] = db0[b * HID + h] - LR * gbv;
        }
    }
}

__global__ void k_upd0f(const float* __restrict__ dW0, const float* __restrict__ x,
                        const float* __restrict__ gb, float* __restrict__ out_dW0) {
    const int n4 = B * IN * HID / 4;
    const int stride = gridDim.x * blockDim.x;
    for (int i = blockIdx.x * blockDim.x + threadIdx.x; i < n4; i += stride) {
        const int j = n4 - 1 - i;
        const int h4 = j & (HID / 4 - 1);
        const int rest = j >> 7;
        const int q = rest & (IN - 1);
        const int b = rest >> 11;
        const float4 dw = ((const float4*)dW0)[j];
        const float xv = x[b * IN + q];
        const float4 g = *(const float4*)(gb + b * HID + h4 * 4);
        vf4 o;
        o.x = dw.x - LR * xv * g.x;
        o.y = dw.y - LR * xv * g.y;
        o.z = dw.z - LR * xv * g.z;
        o.w = dw.w - LR * xv * g.w;
        __builtin_nontemporal_store(o, (vf4*)out_dW0 + j);
    }
}

extern "C" void kernel_launch(void* const* d_in, const int* in_sizes, int n_in,
                              void* d_out, int out_size, void* d_ws, size_t ws_size,
                              hipStream_t stream) {
    (void)in_sizes; (void)n_in; (void)out_size; (void)ws_size;
    const float* x   = (const float*)d_in[0];
    const float* ut  = (const float*)d_in[1];
    const float* W0  = (const float*)d_in[2];
    const float* b0  = (const float*)d_in[3];
    const float* W1  = (const float*)d_in[4];
    const float* b1  = (const float*)d_in[5];
    const float* dW0 = (const float*)d_in[6];
    const float* db0 = (const float*)d_in[7];
    const float* dW1 = (const float*)d_in[8];
    const float* db1 = (const float*)d_in[9];

    float* ws  = (float*)d_ws;
    float* out = (float*)d_out;
    float* zpart  = ws + WS_ZPART;
    float* zopart = ws + WS_ZOPART;
    float* gbw    = ws + WS_GBW;
    int*   ctrs   = (int*)(ws + WS_CTR);

    // zero the barrier counters every replay (graph-capturable async memset)
    hipMemsetAsync(ctrs, 0, NC * 8 * sizeof(int), stream);

    void* args[] = {(void*)&x, (void*)&ut, (void*)&W0, (void*)&b0, (void*)&W1,
                    (void*)&b1, (void*)&dW0, (void*)&db0, (void*)&dW1, (void*)&db1,
                    (void*)&out, (void*)&zpart, (void*)&zopart, (void*)&gbw,
                    (void*)&ctrs};
    hipError_t err = hipLaunchCooperativeKernel((void*)k_mega, dim3(NBLK), dim3(NTHR),
                                                args, 0, stream);
    if (err != hipSuccess) {
        (void)hipGetLastError();
        k_fwd1f<<<dim3(B, FQC), 128, 0, stream>>>(x, W0, dW0, ws + FWS_ZP);
        k_fwd2f<<<dim3(B, 8), 128, 0, stream>>>(ws + FWS_ZP, b0, db0, W1, dW1,
                                                ws + FWS_TANH, ws + FWS_ZOP);
        k_bwd1f<<<dim3(B, 8), 256, 0, stream>>>(ws + FWS_ZOP, b1, db1, ut, W1, dW1,
                                                ws + FWS_TANH, db0,
                                                out + O_L2N, out + O_DB1,
                                                out + O_DW1, out + O_DB0, ws + FWS_GB);
        k_upd0f<<<dim3(4096), 256, 0, stream>>>(dW0, x, ws + FWS_GB, out + O_DW0);
    }
}